// Round 15
// baseline (2404.439 us; speedup 1.0000x reference)
//
#include <hip/hip_runtime.h>
#include <math.h>

// HeterogeneousGNN fused kernel for MI355X (gfx950) — round 15.
// Base = R12 (701 us: 256-thr, (256,2), 2 blocks/CU). R12's two residual costs:
// (a) AGPR demand 144 (acc 128 + g 16) + arch 128 = 272 > 256 -> 16-reg spill;
// (b) 96 barriers/block (2 per 32-node chunk) serializing the GEMM1->LDS->GEMM2
// dataflow at 2 waves/SIMD. R15: each wave's GEMM2 o-slice = the o-tile its own
// GEMM1 produced (acc = 256u x 32o = 128 AGPR), so G never leaves the wave:
// C/D->B-frag relayout done in-register via shfl_xor(.,32)+cndmask (T12
// pattern; both layouts share col=lane&31, verified m74/m101 mapping).
// -> Gc LDS gone, GEMM-phase barriers = ZERO (2 barriers/layer, epilogue only).
// Total demand ~ arch 100 + AGPR 144 = 244 <= 256 -> spill-free.
// LDS = H 64K + stats 8K = 72 KB -> 2 blocks/CU.

typedef float  f32x4  __attribute__((ext_vector_type(4)));
typedef float  f32x16 __attribute__((ext_vector_type(16)));
typedef short  s16x8  __attribute__((ext_vector_type(8)));
typedef unsigned int u32x4 __attribute__((ext_vector_type(4)));
typedef __bf16 bf16x8 __attribute__((ext_vector_type(8)));

#define SOFF 65536   // stats / readout scratch region (8 KB)

__device__ __forceinline__ unsigned short f2bf(float f) {
  __bf16 h = (__bf16)f;                         // RNE, packs to v_cvt
  return __builtin_bit_cast(unsigned short, h);
}
__device__ __forceinline__ float bf2f(unsigned short h) {
  return __builtin_bit_cast(float, (unsigned int)h << 16);
}
__device__ __forceinline__ unsigned short f2bf_rne(float f) {
  unsigned int u = __builtin_bit_cast(unsigned int, f);
  u = (u + 0x7fffu + ((u >> 16) & 1u)) >> 16;
  return (unsigned short)u;
}
__device__ __forceinline__ unsigned int pk2(float lo, float hi) {
  return (unsigned int)f2bf(lo) | ((unsigned int)f2bf(hi) << 16);
}

// H: [256 v][128 d] bf16; XOR (v&15) -> column b128 reads 2-way (free).
__device__ __forceinline__ int haddr(int v, int d) {
  return v * 256 + ((d * 2) ^ ((v & 15) << 4));
}

#define MFMA32(a, b, c) __builtin_amdgcn_mfma_f32_32x32x16_bf16( \
    __builtin_bit_cast(bf16x8, (a)), __builtin_bit_cast(bf16x8, (b)), (c), 0, 0, 0)

// ---- prep: fragment-ordered A3 / W3 (bf16) — unchanged from R12 ----
// A3[h][ut 0..7][vt 0..15][lane][j] = Ac_h[u=ut*32+(lane&31)][v=vt*16+(lane>>5)*8+j]
// W3[hw 0..5][ot 0..3][kt 0..7][lane][j] = W_hw[o=ot*32+(lane&31)][d=kt*16+(lane>>5)*8+j]
__global__ void prep_kernel(const float* __restrict__ alp, const float* __restrict__ aln,
                            const float* __restrict__ wp,  const float* __restrict__ wn,
                            unsigned short* __restrict__ A3, unsigned short* __restrict__ W3) {
  int idx = blockIdx.x * 512 + threadIdx.x;     // 229376 threads total
  if (idx < 131072) {
    int j = idx & 7, lane = (idx >> 3) & 63, vt = (idx >> 9) & 15,
        ut = (idx >> 13) & 7, h = (idx >> 16) & 1;
    int u = ut * 32 + (lane & 31);
    int v = vt * 16 + (lane >> 5) * 8 + j;
    int s = u * 256 + v;
    float ap = 1.f / (1.f + expf(-alp[s]));
    float an = 1.f / (1.f + expf(-aln[s]));
    bool  m  = ap > an;
    float val = h ? (m ? 0.f : -an) : (m ? ap : 0.f);   // neg sign folded
    A3[idx] = f2bf_rne(val);
  } else {
    int k = idx - 131072;                       // 0 .. 98303
    int j = k & 7, lane = (k >> 3) & 63, kt = (k >> 9) & 7,
        ot = (k >> 12) & 3, hw = (k >> 14);     // hw = l*2 + (0=pos,1=neg)
    int o = ot * 32 + (lane & 31);
    int d = kt * 16 + (lane >> 5) * 8 + j;
    const float* src = (hw & 1) ? wn : wp;
    W3[k] = f2bf_rne(src[(hw >> 1) * 16384 + o * 128 + d]);
  }
}

__global__ __launch_bounds__(256, 2) void gnn_kernel(
    const float* __restrict__ X,
    const unsigned short* __restrict__ A3,
    const unsigned short* __restrict__ W3,
    const float* __restrict__ ln_g, const float* __restrict__ ln_b,
    const float* __restrict__ ro_g, const float* __restrict__ ro_b,
    float* __restrict__ out) {
  extern __shared__ char smem[];
  const int  tid  = threadIdx.x;
  const int  wid  = tid >> 6;       // 0..3: this wave's o-slice = wid*32
  const int  lane = tid & 63;
  const int  l31  = lane & 31;
  const int  khi  = (lane >> 5) * 8;
  const bool hib  = lane >= 32;
  const int  b    = blockIdx.x;

  // ---- stage H = bf16(X[b]) into LDS ----
  {
    const float4* Xb = (const float4*)(X + (size_t)b * 256 * 128);
#pragma unroll 8
    for (int i = 0; i < 32; ++i) {
      int idx = tid + i * 256;                 // 8192 float4 chunks
      int v = idx >> 5, d = (idx & 31) * 4;
      float4 f = Xb[idx];
      ushort4 p;
      p.x = f2bf(f.x); p.y = f2bf(f.y); p.z = f2bf(f.z); p.w = f2bf(f.w);
      *(ushort4*)(smem + haddr(v, d)) = p;
    }
  }
  __syncthreads();

  float* stats = (float*)(smem + SOFF);        // [u 0..255][wid 0..3] float2

  for (int l = 0; l < 3; ++l) {
    f32x16 acc[8];                             // 256u x 32o per wave (128 AGPR)
#pragma unroll
    for (int ut = 0; ut < 8; ++ut)
#pragma unroll
      for (int r = 0; r < 16; ++r) acc[ut][r] = 0.f;

    for (int h = 0; h < 2; ++h) {
      const unsigned short* Wb = W3 + (size_t)(((l * 2 + h) * 4 + wid) * 8) * 512;
      const unsigned short* Ab = A3 + (size_t)h * 65536;

      s16x8 wreg[8];                           // this wave's W o-tile (32 regs)
#pragma unroll
      for (int kt = 0; kt < 8; ++kt)
        wreg[kt] = *(const s16x8*)(Wb + (size_t)kt * 512 + lane * 8);

#pragma unroll 1
      for (int c = 0; c < 8; ++c) {            // v-chunks of 32 nodes
        // ---- GEMM1 (in regs): g = H[c][32v] @ W^T -> 32v x 32o tile ----
        f32x16 g;
#pragma unroll
        for (int r = 0; r < 16; ++r) g[r] = 0.f;
        const int v0 = c * 32 + l31;
#pragma unroll
        for (int kt = 0; kt < 8; ++kt) {       // K = d = 128
          s16x8 ha = *(const s16x8*)(smem + haddr(v0, kt * 16 + khi));
          g = MFMA32(ha, wreg[kt], g);
        }
        // ---- C/D -> B-frag relayout, fully in-register (no LDS!) ----
        // C/D: lane(hi,l31) holds v=(r&3)+8(r>>2)+4hi at o=l31 (m74/m101).
        // pack r-pairs: w0=v{0,1} w1=v{2,3} w2=v{8,9} w3=v{10,11}
        //              w4=v{16,17} w5=v{18,19} w6=v{24,25} w7=v{26,27} (+4 if hi)
        unsigned int w[8], sx[8];
#pragma unroll
        for (int i = 0; i < 8; ++i) w[i] = pk2(g[2 * i], g[2 * i + 1]);
#pragma unroll
        for (int i = 0; i < 8; ++i)
          sx[i] = (unsigned int)__shfl_xor((int)w[i], 32);
        // B-frag kt2=0 (v 0..15):  hi=0 [w0 w1 sx0 sx1], hi=1 [sx2 sx3 w2 w3]
        // B-frag kt2=1 (v 16..31): hi=0 [w4 w5 sx4 sx5], hi=1 [sx6 sx7 w6 w7]
        u32x4 fv0 = { hib ? sx[2] : w[0], hib ? sx[3] : w[1],
                      hib ? w[2] : sx[0], hib ? w[3] : sx[1] };
        u32x4 fv1 = { hib ? sx[6] : w[4], hib ? sx[7] : w[5],
                      hib ? w[6] : sx[4], hib ? w[7] : sx[5] };
        s16x8 bf0 = __builtin_bit_cast(s16x8, fv0);
        s16x8 bf1 = __builtin_bit_cast(s16x8, fv1);

        // ---- GEMM2: acc[256u x 32o] += A[u, 32v-chunk] @ g ----
#pragma unroll
        for (int ut = 0; ut < 8; ++ut) {
          s16x8 a0 = *(const s16x8*)(Ab + (size_t)(ut * 16 + c * 2 + 0) * 512 + lane * 8);
          acc[ut] = MFMA32(a0, bf0, acc[ut]);
        }
#pragma unroll
        for (int ut = 0; ut < 8; ++ut) {
          s16x8 a1 = *(const s16x8*)(Ab + (size_t)(ut * 16 + c * 2 + 1) * 512 + lane * 8);
          acc[ut] = MFMA32(a1, bf1, acc[ut]);
        }
      } // chunks
    } // halves  — NOTE: zero barriers in the whole GEMM phase

    // ---- epilogue: exact GELU + cross-wave LayerNorm -> H' ----
    const float lgv = ln_g[l * 128 + wid * 32 + l31];
    const float lbv = ln_b[l * 128 + wid * 32 + l31];
#pragma unroll
    for (int ut = 0; ut < 8; ++ut)
#pragma unroll
      for (int r = 0; r < 16; ++r) {
        float x = acc[ut][r];
        x = 0.5f * x * (1.f + erff(x * 0.70710678f));
        acc[ut][r] = x;
        float s1 = x, s2 = x * x;
#pragma unroll
        for (int m = 1; m < 32; m <<= 1) {     // reduce this wave's 32-o slice
          s1 += __shfl_xor(s1, m);
          s2 += __shfl_xor(s2, m);
        }
        if (l31 == r) {                        // lanes r, r+32 write their u
          int u = ut * 32 + (r & 3) + 8 * (r >> 2) + (hib ? 4 : 0);
          float2 pw; pw.x = s1; pw.y = s2;
          *(float2*)&stats[u * 8 + wid * 2] = pw;
        }
      }
    __syncthreads();                           // barrier 1: stats ready (and all
                                               // H reads of this layer are done)
#pragma unroll
    for (int ut = 0; ut < 8; ++ut)
#pragma unroll
      for (int r = 0; r < 16; ++r) {
        int u = ut * 32 + (r & 3) + 8 * (r >> 2) + (hib ? 4 : 0);
        float mu = 0.f, rs = 0.f;
        if (l31 == r) {                        // designated lane computes mu/rs
          f32x4 s01 = *(const f32x4*)&stats[u * 8];
          f32x4 s23 = *(const f32x4*)&stats[u * 8 + 4];
          float s1 = s01[0] + s01[2] + s23[0] + s23[2];
          float s2 = s01[1] + s01[3] + s23[1] + s23[3];
          mu = s1 * (1.f / 128.f);
          float var = s2 * (1.f / 128.f) - mu * mu;
          rs = rsqrtf(var + 1e-5f);
        }
        mu = __shfl(mu, (lane & 32) + r);      // broadcast within hi-group
        rs = __shfl(rs, (lane & 32) + r);
        float y = (acc[ut][r] - mu) * rs * lgv + lbv;
        *(unsigned short*)(smem + haddr(u, wid * 32 + l31)) = f2bf(y);
      }
    __syncthreads();                           // barrier 2: H' ready
  } // layers

  // ---- readout: mean over nodes + final LN ----
  {
    int d   = tid & 127;
    int grp = tid >> 7;                        // 0..1, 128 rows each
    float s = 0.f;
    for (int v = grp * 128; v < grp * 128 + 128; ++v)
      s += bf2f(*(const unsigned short*)(smem + haddr(v, d)));
    float* red = (float*)(smem + SOFF);
    red[grp * 128 + d] = s;
    __syncthreads();
    if (tid < 128) {
      red[256 + tid] = (red[tid] + red[128 + tid]) * (1.f / 256.f);
    }
    __syncthreads();
    if (tid < 64) {
      float a  = red[256 + tid];
      float b2 = red[256 + 64 + tid];
      float s1 = a + b2, s2 = a * a + b2 * b2;
#pragma unroll
      for (int m = 1; m < 64; m <<= 1) {
        s1 += __shfl_xor(s1, m);
        s2 += __shfl_xor(s2, m);
      }
      float mu  = s1 * (1.f / 128.f);
      float var = s2 * (1.f / 128.f) - mu * mu;
      float rs  = rsqrtf(var + 1e-5f);
      out[(size_t)b * 128 + tid]      = (a  - mu) * rs * ro_g[tid]      + ro_b[tid];
      out[(size_t)b * 128 + 64 + tid] = (b2 - mu) * rs * ro_g[64 + tid] + ro_b[64 + tid];
    }
  }
}

extern "C" void kernel_launch(void* const* d_in, const int* in_sizes, int n_in,
                              void* d_out, int out_size, void* d_ws, size_t ws_size,
                              hipStream_t stream) {
  const float* X   = (const float*)d_in[0];
  const float* alp = (const float*)d_in[1];
  const float* aln = (const float*)d_in[2];
  const float* wp  = (const float*)d_in[3];
  const float* wn  = (const float*)d_in[4];
  const float* lng = (const float*)d_in[5];
  const float* lnb = (const float*)d_in[6];
  const float* rog = (const float*)d_in[7];
  const float* rob = (const float*)d_in[8];
  float* out = (float*)d_out;

  unsigned short* A3 = (unsigned short*)d_ws;          // 131072 bf16 = 256 KB
  unsigned short* W3 = A3 + 131072;                    //  98304 bf16 = 192 KB

  (void)hipFuncSetAttribute(reinterpret_cast<const void*>(gnn_kernel),
                            hipFuncAttributeMaxDynamicSharedMemorySize, 73728);

  prep_kernel<<<448, 512, 0, stream>>>(alp, aln, wp, wn, A3, W3);
  gnn_kernel<<<2048, 256, 73728, stream>>>(X, A3, W3, lng, lnb, rog, rob, out);
}

// Round 16
// 653.979 us; speedup vs baseline: 3.6766x; 3.6766x over previous
//
#include <hip/hip_runtime.h>
#include <math.h>

// HeterogeneousGNN fused kernel for MI355X (gfx950) — round 16.
// Base = R12 (verified best, 701 us). R15's zero-barrier rewrite spilled
// (register estimate off by ~60; reverted). R16 = R12 + the individually-
// verified deltas only, each with >=40 regs slack:
//  (a) native bf16 casts (R13: VALU down, correctness same)
//  (b) pa[4] A-frag prefetch before GEMM1 (latency hidden under GEMM1+bars)
//  (c) wreg[8] hoist kept (R13's removal caused its regression)
//  (d) GEMM2 bf loads transient per-nt (peak -12 regs vs bf[4] array)
// Arch ~92 + AGPR 144 = ~236 <= 256 -> spill headroom restored.

typedef float  f32x4  __attribute__((ext_vector_type(4)));
typedef float  f32x16 __attribute__((ext_vector_type(16)));
typedef short  s16x8  __attribute__((ext_vector_type(8)));
typedef __bf16 bf16x8 __attribute__((ext_vector_type(8)));

#define GOFF 65536   // Gc region byte offset (10240 B)

__device__ __forceinline__ unsigned short f2bf(float f) {
  __bf16 h = (__bf16)f;                         // RNE, packs to v_cvt
  return __builtin_bit_cast(unsigned short, h);
}
__device__ __forceinline__ float bf2f(unsigned short h) {
  return __builtin_bit_cast(float, (unsigned int)h << 16);
}
__device__ __forceinline__ unsigned short f2bf_rne(float f) {
  unsigned int u = __builtin_bit_cast(unsigned int, f);
  u = (u + 0x7fffu + ((u >> 16) & 1u)) >> 16;
  return (unsigned short)u;
}

// H: [256 v][128 d] bf16; XOR (v&15) -> column b128 reads 2-way (free).
__device__ __forceinline__ int haddr(int v, int d) {
  return v * 256 + ((d * 2) ^ ((v & 15) << 4));
}
// Gc^T: [128 o][32 v] bf16, 80-B row stride; slot(o)=5*o mod 8 -> 4-way floor.
__device__ __forceinline__ int gaddr(int o, int vr) {
  return GOFF + o * 80 + vr * 2;
}

#define MFMA32(a, b, c) __builtin_amdgcn_mfma_f32_32x32x16_bf16( \
    __builtin_bit_cast(bf16x8, (a)), __builtin_bit_cast(bf16x8, (b)), (c), 0, 0, 0)

// ---- prep: fragment-ordered A3 / W3 (bf16) ----
// A3[h][ut 0..7][vt 0..15][lane][j] = Ac_h[u=ut*32+(lane&31)][v=vt*16+(lane>>5)*8+j]
// W3[hw 0..5][ot 0..3][kt 0..7][lane][j] = W_hw[o=ot*32+(lane&31)][d=kt*16+(lane>>5)*8+j]
__global__ void prep_kernel(const float* __restrict__ alp, const float* __restrict__ aln,
                            const float* __restrict__ wp,  const float* __restrict__ wn,
                            unsigned short* __restrict__ A3, unsigned short* __restrict__ W3) {
  int idx = blockIdx.x * 512 + threadIdx.x;     // 229376 threads total
  if (idx < 131072) {
    int j = idx & 7, lane = (idx >> 3) & 63, vt = (idx >> 9) & 15,
        ut = (idx >> 13) & 7, h = (idx >> 16) & 1;
    int u = ut * 32 + (lane & 31);
    int v = vt * 16 + (lane >> 5) * 8 + j;
    int s = u * 256 + v;
    float ap = 1.f / (1.f + expf(-alp[s]));
    float an = 1.f / (1.f + expf(-aln[s]));
    bool  m  = ap > an;
    float val = h ? (m ? 0.f : -an) : (m ? ap : 0.f);   // neg sign folded
    A3[idx] = f2bf_rne(val);
  } else {
    int k = idx - 131072;                       // 0 .. 98303
    int j = k & 7, lane = (k >> 3) & 63, kt = (k >> 9) & 7,
        ot = (k >> 12) & 3, hw = (k >> 14);     // hw = l*2 + (0=pos,1=neg)
    int o = ot * 32 + (lane & 31);
    int d = kt * 16 + (lane >> 5) * 8 + j;
    const float* src = (hw & 1) ? wn : wp;
    W3[k] = f2bf_rne(src[(hw >> 1) * 16384 + o * 128 + d]);
  }
}

__global__ __launch_bounds__(256, 2) void gnn_kernel(
    const float* __restrict__ X,
    const unsigned short* __restrict__ A3,
    const unsigned short* __restrict__ W3,
    const float* __restrict__ ln_g, const float* __restrict__ ln_b,
    const float* __restrict__ ro_g, const float* __restrict__ ro_b,
    float* __restrict__ out) {
  extern __shared__ char smem[];
  const int tid  = threadIdx.x;
  const int wid  = tid >> 6;        // 0..3
  const int lane = tid & 63;
  const int l31  = lane & 31;
  const int hi   = lane >> 5;
  const int b    = blockIdx.x;

  // ---- stage H = bf16(X[b]) into LDS ----
  {
    const float4* Xb = (const float4*)(X + (size_t)b * 256 * 128);
#pragma unroll 8
    for (int i = 0; i < 32; ++i) {
      int idx = tid + i * 256;                 // 8192 float4 chunks
      int v = idx >> 5, d = (idx & 31) * 4;
      float4 f = Xb[idx];
      ushort4 p;
      p.x = f2bf(f.x); p.y = f2bf(f.y); p.z = f2bf(f.z); p.w = f2bf(f.w);
      *(ushort4*)(smem + haddr(v, d)) = p;
    }
  }
  __syncthreads();

  f32x16 acc[2][4];                  // wave tile: u = wid*64..+64, o = 0..128
  for (int l = 0; l < 3; ++l) {
#pragma unroll
    for (int mt = 0; mt < 2; ++mt)
#pragma unroll
      for (int nt = 0; nt < 4; ++nt)
#pragma unroll
        for (int r = 0; r < 16; ++r) acc[mt][nt][r] = 0.f;

    for (int h = 0; h < 2; ++h) {
      const unsigned short* Wb = W3 + (size_t)(((l * 2 + h) * 4 + wid) * 8) * 512;
      const unsigned short* Ab = A3 + (size_t)((h * 8 + wid * 2) * 16) * 512;

      // (c) hoisted W o-tile fragments, reused by all 8 chunks
      s16x8 wreg[8];
#pragma unroll
      for (int kt = 0; kt < 8; ++kt)
        wreg[kt] = *(const s16x8*)(Wb + (size_t)kt * 512 + lane * 8);

      for (int c = 0; c < 8; ++c) {            // v-chunks of 32 nodes
        // (b) prefetch this chunk's A fragments (consumed after the barriers)
        s16x8 pa[4];
#pragma unroll
        for (int kt = 0; kt < 2; ++kt) {
          pa[kt * 2 + 0] = *(const s16x8*)(Ab + (size_t)(0 * 16 + c * 2 + kt) * 512 + lane * 8);
          pa[kt * 2 + 1] = *(const s16x8*)(Ab + (size_t)(1 * 16 + c * 2 + kt) * 512 + lane * 8);
        }

        // ---- GEMM1: Gc[32v][128o] = H[c] @ W^T; one 32x32 tile per wave ----
        f32x16 g0;
#pragma unroll
        for (int r = 0; r < 16; ++r) g0[r] = 0.f;
        const int v0 = c * 32 + l31;
#pragma unroll
        for (int kt = 0; kt < 8; ++kt) {       // K = d = 128
          s16x8 ha = *(const s16x8*)(smem + haddr(v0, kt * 16 + hi * 8));
          g0 = MFMA32(ha, wreg[kt], g0);
        }
        __syncthreads();                       // prev chunk's GEMM2 reads done
        {
          const int og = wid * 32 + l31;       // C/D col = lane&31
#pragma unroll
          for (int rq = 0; rq < 4; ++rq) {     // rows v = (r&3)+8*(r>>2)+4*hi
            int vr = rq * 8 + hi * 4;
            ushort4 p;
            p.x = f2bf(g0[rq*4+0]); p.y = f2bf(g0[rq*4+1]);
            p.z = f2bf(g0[rq*4+2]); p.w = f2bf(g0[rq*4+3]);
            *(ushort4*)(smem + gaddr(og, vr)) = p;
          }
        }
        __syncthreads();                       // Gc ready

        // ---- GEMM2: acc += Ac_h[u, 32c..] @ Gc; 64u x 128o per wave ----
        // (d) bf loaded transiently per o-tile
#pragma unroll
        for (int kt = 0; kt < 2; ++kt) {       // K = v-chunk = 32
#pragma unroll
          for (int nt = 0; nt < 4; ++nt) {
            s16x8 bf = *(const s16x8*)(smem + gaddr(nt * 32 + l31, kt * 16 + hi * 8));
            acc[0][nt] = MFMA32(pa[kt * 2 + 0], bf, acc[0][nt]);
            acc[1][nt] = MFMA32(pa[kt * 2 + 1], bf, acc[1][nt]);
          }
        }
      } // chunks
    } // halves

    // ---- epilogue: exact GELU + wave-local LayerNorm -> H ----
    {
      float lg[4], lb[4];
#pragma unroll
      for (int nt = 0; nt < 4; ++nt) {
        lg[nt] = ln_g[l * 128 + nt * 32 + l31];
        lb[nt] = ln_b[l * 128 + nt * 32 + l31];
      }
#pragma unroll
      for (int mt = 0; mt < 2; ++mt)
#pragma unroll
        for (int r = 0; r < 16; ++r) {
          float x0 = acc[mt][0][r]; x0 = 0.5f * x0 * (1.f + erff(x0 * 0.70710678f));
          float x1 = acc[mt][1][r]; x1 = 0.5f * x1 * (1.f + erff(x1 * 0.70710678f));
          float x2 = acc[mt][2][r]; x2 = 0.5f * x2 * (1.f + erff(x2 * 0.70710678f));
          float x3 = acc[mt][3][r]; x3 = 0.5f * x3 * (1.f + erff(x3 * 0.70710678f));
          acc[mt][0][r] = x0; acc[mt][1][r] = x1;
          acc[mt][2][r] = x2; acc[mt][3][r] = x3;
          float s1 = x0 + x1 + x2 + x3;
          float s2 = x0 * x0 + x1 * x1 + x2 * x2 + x3 * x3;
#pragma unroll
          for (int m = 1; m < 32; m <<= 1) {   // full row (128 cols) reduce
            s1 += __shfl_xor(s1, m);
            s2 += __shfl_xor(s2, m);
          }
          float mu  = s1 * (1.f / 128.f);
          float var = s2 * (1.f / 128.f) - mu * mu;
          float rs  = rsqrtf(var + 1e-5f);
          int u = wid * 64 + mt * 32 + (r & 3) + 8 * ((r >> 2) & 3) + 4 * hi;
#pragma unroll
          for (int nt = 0; nt < 4; ++nt) {
            float y = (acc[mt][nt][r] - mu) * rs * lg[nt] + lb[nt];
            *(unsigned short*)(smem + haddr(u, nt * 32 + l31)) = f2bf(y);
          }
        }
    }
    __syncthreads();                           // H' ready for next layer
  } // layers

  // ---- readout: mean over nodes + final LN ----
  {
    int d   = tid & 127;
    int grp = tid >> 7;                        // 0..1, 128 rows each
    float s = 0.f;
    for (int v = grp * 128; v < grp * 128 + 128; ++v)
      s += bf2f(*(const unsigned short*)(smem + haddr(v, d)));
    float* red = (float*)(smem + GOFF);        // Gc region is dead now
    red[grp * 128 + d] = s;
    __syncthreads();
    if (tid < 128) {
      red[256 + tid] = (red[tid] + red[128 + tid]) * (1.f / 256.f);
    }
    __syncthreads();
    if (tid < 64) {
      float a  = red[256 + tid];
      float b2 = red[256 + 64 + tid];
      float s1 = a + b2, s2 = a * a + b2 * b2;
#pragma unroll
      for (int m = 1; m < 64; m <<= 1) {
        s1 += __shfl_xor(s1, m);
        s2 += __shfl_xor(s2, m);
      }
      float mu  = s1 * (1.f / 128.f);
      float var = s2 * (1.f / 128.f) - mu * mu;
      float rs  = rsqrtf(var + 1e-5f);
      out[(size_t)b * 128 + tid]      = (a  - mu) * rs * ro_g[tid]      + ro_b[tid];
      out[(size_t)b * 128 + 64 + tid] = (b2 - mu) * rs * ro_g[64 + tid] + ro_b[64 + tid];
    }
  }
}

extern "C" void kernel_launch(void* const* d_in, const int* in_sizes, int n_in,
                              void* d_out, int out_size, void* d_ws, size_t ws_size,
                              hipStream_t stream) {
  const float* X   = (const float*)d_in[0];
  const float* alp = (const float*)d_in[1];
  const float* aln = (const float*)d_in[2];
  const float* wp  = (const float*)d_in[3];
  const float* wn  = (const float*)d_in[4];
  const float* lng = (const float*)d_in[5];
  const float* lnb = (const float*)d_in[6];
  const float* rog = (const float*)d_in[7];
  const float* rob = (const float*)d_in[8];
  float* out = (float*)d_out;

  unsigned short* A3 = (unsigned short*)d_ws;          // 131072 bf16 = 256 KB
  unsigned short* W3 = A3 + 131072;                    //  98304 bf16 = 192 KB

  (void)hipFuncSetAttribute(reinterpret_cast<const void*>(gnn_kernel),
                            hipFuncAttributeMaxDynamicSharedMemorySize, 75776);

  prep_kernel<<<448, 512, 0, stream>>>(alp, aln, wp, wn, A3, W3);
  gnn_kernel<<<2048, 256, 75776, stream>>>(X, A3, W3, lng, lnb, rog, rob, out);
}